// Round 2
// baseline (6584.998 us; speedup 1.0000x reference)
//
#include <hip/hip_runtime.h>
#include <stdint.h>

// ---------------------------------------------------------------------------
// Critic: encoder -> 255-step LSTM (U=256, D_in=256) -> 1-unit relu head. B=512
//
// Round-2 design (fix: weight streaming wall from round 1):
//  - 256 blocks = 32 batch-tiles x 8 unit-groups; block owns 16 rows x 32 units.
//  - Weight slice (128 KB bf16) register-resident: 128 VGPRs/lane, 4 waves.
//  - Per-step h exchange between the 8 unit-group blocks of a tile via global
//    ping-pong buffer + agent-scope atomics; per-(g,w) flags, acquire polls.
//  - Gate interleave: acc0 = {i|f}, acc1 = {g|o}; lane pair (cid, cid^8)
//    exchanges via shfl_xor(8); c-state in registers.
//  - x double-buffered in LDS (bf16), prefetched; 1 __syncthreads per step.
// ---------------------------------------------------------------------------

#define TSTEPS 128
#define NSTEP  (2 * TSTEPS - 1)   // 255

typedef __attribute__((ext_vector_type(8))) short short8;   // 8 x bf16
typedef __attribute__((ext_vector_type(4))) float f32x4;

__device__ __forceinline__ unsigned short f2bf(float f) {
    union { float f; unsigned int u; } v; v.f = f;
    unsigned int r = v.u + 0x7FFFu + ((v.u >> 16) & 1u);   // RNE
    return (unsigned short)(r >> 16);
}
__device__ __forceinline__ float bf2f(unsigned short u) {
    union { float f; unsigned int v; } x; x.v = ((unsigned int)u) << 16; return x.f;
}
__device__ __forceinline__ float fexp2(float x) { return __builtin_amdgcn_exp2f(x); }
__device__ __forceinline__ float frcp(float x)  { return __builtin_amdgcn_rcpf(x); }
__device__ __forceinline__ float sigm(float x)  { return frcp(1.0f + fexp2(-1.44269504f * x)); }
__device__ __forceinline__ float tanh_(float x) { return 1.0f - 2.0f * frcp(1.0f + fexp2(2.88539008f * x)); }

// ---------------------------------------------------------------------------
// Encoder: state = relu(concat(ms,rs,re,im) @ Wc + bc)   [512,256] fp32
// ---------------------------------------------------------------------------
__global__ __launch_bounds__(256)
void encoder_kernel(const float* __restrict__ motion, const float* __restrict__ robot,
                    const float* __restrict__ osr, const float* __restrict__ osi,
                    const float* __restrict__ ore, const float* __restrict__ oie,
                    const float* __restrict__ Wm, const float* __restrict__ bm,
                    const float* __restrict__ Wr, const float* __restrict__ br,
                    const float* __restrict__ Wre, const float* __restrict__ bre,
                    const float* __restrict__ Wim, const float* __restrict__ bim,
                    const float* __restrict__ Wc, const float* __restrict__ bc,
                    float* __restrict__ state)
{
    __shared__ float in_m[16][64];
    __shared__ float in_r[16][128];
    __shared__ float in_re[16][128];
    __shared__ float in_im[16][128];
    __shared__ float catb[16 * 768];
    const int t = threadIdx.x;
    const int m0 = blockIdx.x * 16;

    // stage inputs to LDS (coalesced float4)
    {
        int idx = t * 4; int row = idx >> 6, col = idx & 63;
        *(float4*)&in_m[row][col]       = *(const float4*)(motion + (m0 + row) * 64 + col);
        *(float4*)&in_re[row][col]      = *(const float4*)(osr + (m0 + row) * 64 + col);
        *(float4*)&in_re[row][64 + col] = *(const float4*)(ore + (m0 + row) * 64 + col);
        *(float4*)&in_im[row][col]      = *(const float4*)(osi + (m0 + row) * 64 + col);
        *(float4*)&in_im[row][64 + col] = *(const float4*)(oie + (m0 + row) * 64 + col);
    }
    for (int p = 0; p < 2; ++p) {
        int idx = (t + p * 256) * 4; int row = idx >> 7, col = idx & 127;
        *(float4*)&in_r[row][col] = *(const float4*)(robot + (m0 + row) * 128 + col);
    }
    __syncthreads();

    // Phase A: concat [16][768] = [ms 256 | rs 256 | re 128 | im 128]
    for (int row = 0; row < 16; ++row) {
        {
            float s = bm[t];
            for (int k = 0; k < 64; ++k) s += in_m[row][k] * Wm[k * 256 + t];
            catb[row * 768 + t] = fmaxf(s, 0.0f);
        }
        {
            float s = br[t];
            for (int k = 0; k < 128; ++k) s += in_r[row][k] * Wr[k * 256 + t];
            catb[row * 768 + 256 + t] = fmaxf(s, 0.0f);
        }
        if (t < 128) {
            float s = bre[t];
            for (int k = 0; k < 128; ++k) s += in_re[row][k] * Wre[k * 128 + t];
            catb[row * 768 + 512 + t] = fmaxf(s, 0.0f);
        } else {
            const int u = t - 128;
            float s = bim[u];
            for (int k = 0; k < 128; ++k) s += in_im[row][k] * Wim[k * 128 + u];
            catb[row * 768 + 640 + u] = fmaxf(s, 0.0f);
        }
    }
    __syncthreads();

    // Phase B: state = relu(cat @ Wc + bc)
    for (int r0 = 0; r0 < 16; r0 += 4) {
        float a0 = bc[t], a1 = bc[t], a2 = bc[t], a3 = bc[t];
        for (int j = 0; j < 768; ++j) {
            const float wv = Wc[j * 256 + t];
            a0 += catb[(r0 + 0) * 768 + j] * wv;
            a1 += catb[(r0 + 1) * 768 + j] * wv;
            a2 += catb[(r0 + 2) * 768 + j] * wv;
            a3 += catb[(r0 + 3) * 768 + j] * wv;
        }
        state[(m0 + r0 + 0) * 256 + t] = fmaxf(a0, 0.0f);
        state[(m0 + r0 + 1) * 256 + t] = fmaxf(a1, 0.0f);
        state[(m0 + r0 + 2) * 256 + t] = fmaxf(a2, 0.0f);
        state[(m0 + r0 + 3) * 256 + t] = fmaxf(a3, 0.0f);
    }
}

// ---------------------------------------------------------------------------
// Prep: W2[n3][512] bf16, n3 in block-local permuted col order; K = [Wk | Wrk].
//   n3: g = n3>>7, j = n3&127, w = j>>5, t=(j>>4)&1, c=j&15
//   gate = 2t + (c>>3), unit = 32g + 8w + (c&7), orig col = gate*256 + unit.
// Also zeroes the exchange flags.
// ---------------------------------------------------------------------------
__global__ __launch_bounds__(256)
void prep_kernel(const float* __restrict__ Wk, const float* __restrict__ Wrk,
                 unsigned short* __restrict__ W2, unsigned int* __restrict__ flags)
{
    const int n3 = blockIdx.x;
    const int k = threadIdx.x;
    const int g = n3 >> 7, j = n3 & 127;
    const int w = j >> 5, tt = (j >> 4) & 1, c = j & 15;
    const int gam = 2 * tt + (c >> 3);
    const int u = g * 32 + w * 8 + (c & 7);
    const int no = gam * 256 + u;
    W2[(size_t)n3 * 512 + k]       = f2bf(Wk[(size_t)k * 1024 + no]);
    W2[(size_t)n3 * 512 + 256 + k] = f2bf(Wrk[(size_t)k * 1024 + no]);
    if (n3 == 0) {
        for (int i = k; i < 1024; i += 256) flags[i * 16] = 0u;
    }
}

// ---------------------------------------------------------------------------
// LSTM: 256 blocks x 256 threads (4 waves). Block (m = bx&31, g = bx>>5).
// ---------------------------------------------------------------------------
__global__ __launch_bounds__(256, 1)
void lstm_kernel(const float* __restrict__ hist, const float* __restrict__ act,
                 const float* __restrict__ state,
                 const unsigned short* __restrict__ W2, const float* __restrict__ bl,
                 const float* __restrict__ Wo, const float* __restrict__ bo_p,
                 unsigned short* __restrict__ hbuf, unsigned int* __restrict__ flags,
                 float* __restrict__ hfin, float* __restrict__ out)
{
    __shared__ unsigned short xb[2][16 * 264];   // x, bf16, double-buffered
    __shared__ unsigned short hx[4][16 * 8];     // per-wave h transpose scratch

    const int tid  = threadIdx.x;
    const int w    = tid >> 6;
    const int lane = tid & 63;
    const int q    = lane >> 4;
    const int cid  = lane & 15;
    const int bx   = blockIdx.x;
    const int m    = bx & 31;
    const int g    = bx >> 5;
    const int m0   = m * 16;

    // ---- register-resident weight slice: 2 tiles x 16 K-frags x short8 ----
    short8 Bk[2][16];
#pragma unroll
    for (int t = 0; t < 2; ++t) {
        const unsigned short* bp = W2 + (size_t)(g * 128 + w * 32 + t * 16 + cid) * 512 + q * 8;
#pragma unroll
        for (int kk = 0; kk < 16; ++kk)
            Bk[t][kk] = *(const short8*)(bp + kk * 32);
    }

    // ---- c-state + biases for this lane's unit ----
    const int u = g * 32 + w * 8 + (cid & 7);
    float cc[4];
#pragma unroll
    for (int r = 0; r < 4; ++r) cc[r] = state[(size_t)(m0 + q * 4 + r) * 256 + u];
    const float bi  = bl[u];
    const float bff = bl[256 + u];
    const float bg  = bl[512 + u];
    const float bo2 = bl[768 + u];

    // ---- stage x^0 into xb[0] ----
    {
        const int row = tid >> 4, c16 = tid & 15;
        const float* xs = hist + ((size_t)(m0 + row) * TSTEPS + 0) * 256;
#pragma unroll
        for (int jj = 0; jj < 4; ++jj) {
            const int col = jj * 64 + c16 * 4;
            const float4 v = *(const float4*)(xs + col);
            unsigned long long pk = (unsigned long long)f2bf(v.x)
                | ((unsigned long long)f2bf(v.y) << 16)
                | ((unsigned long long)f2bf(v.z) << 32)
                | ((unsigned long long)f2bf(v.w) << 48);
            *(unsigned long long*)&xb[0][row * 264 + col] = pk;
        }
    }

    // ---- publish h^0 = bf16(state slice) to slot 0, flag = 1 ----
    if (lane < 32) {
        const int r = lane >> 1, half = lane & 1;
        const int u0 = g * 32 + w * 8 + half * 4;
        const float4 v = *(const float4*)(state + (size_t)(m0 + r) * 256 + u0);
        unsigned long long pk = (unsigned long long)f2bf(v.x)
            | ((unsigned long long)f2bf(v.y) << 16)
            | ((unsigned long long)f2bf(v.z) << 32)
            | ((unsigned long long)f2bf(v.w) << 48);
        __hip_atomic_store((unsigned long long*)hbuf + ((size_t)(0 * 32 + m) * 16 + r) * 64 + (u0 >> 2),
                           pk, __ATOMIC_RELAXED, __HIP_MEMORY_SCOPE_AGENT);
    }
    if (lane == 32)
        __hip_atomic_store(&flags[(m * 32 + g * 4 + w) * 16], 1u,
                           __ATOMIC_RELEASE, __HIP_MEMORY_SCOPE_AGENT);
    __syncthreads();

    // ---- main recurrence ----
    float4 xp[4];
    float h[4];
    for (int s = 0; s < NSTEP; ++s) {
        const unsigned target = (unsigned)(s + 1);
        // wait for all 32 (g,w) slices of h^s
        for (;;) {
            unsigned v = 0xFFFFFFFFu;
            if (lane < 32)
                v = __hip_atomic_load(&flags[(m * 32 + lane) * 16],
                                      __ATOMIC_ACQUIRE, __HIP_MEMORY_SCOPE_AGENT);
            if (!__any((int)(v < target))) break;
            __builtin_amdgcn_s_sleep(1);
        }

        // prefetch x^{s+1} (HBM) into registers
        if (s < NSTEP - 1) {
            const int sn = s + 1;
            const int row = tid >> 4, c16 = tid & 15;
            const float* xs = (sn < TSTEPS - 1)
                ? hist + ((size_t)(m0 + row) * TSTEPS + sn) * 256
                : act  + ((size_t)(m0 + row) * TSTEPS + (sn - (TSTEPS - 1))) * 256;
#pragma unroll
            for (int jj = 0; jj < 4; ++jj)
                xp[jj] = *(const float4*)(xs + jj * 64 + c16 * 4);
        }

        // h^s A-fragments from global ping-pong (L2/L3), agent-scope loads
        unsigned long long ha[8], hb2[8];
        const unsigned long long* hbase =
            (const unsigned long long*)hbuf + ((size_t)((s & 1) * 32 + m) * 16 + cid) * 64 + 2 * q;
#pragma unroll
        for (int kk = 0; kk < 8; ++kk) {
            ha[kk]  = __hip_atomic_load(hbase + kk * 8,     __ATOMIC_RELAXED, __HIP_MEMORY_SCOPE_AGENT);
            hb2[kk] = __hip_atomic_load(hbase + kk * 8 + 1, __ATOMIC_RELAXED, __HIP_MEMORY_SCOPE_AGENT);
        }

        f32x4 acc0 = {0.f, 0.f, 0.f, 0.f};
        f32x4 acc1 = {0.f, 0.f, 0.f, 0.f};

        // z += x @ Wk
        const unsigned short* xrow = &xb[s & 1][cid * 264 + q * 8];
#pragma unroll
        for (int kk = 0; kk < 8; ++kk) {
            const short8 a = *(const short8*)(xrow + kk * 32);
            acc0 = __builtin_amdgcn_mfma_f32_16x16x32_bf16(a, Bk[0][kk], acc0, 0, 0, 0);
            acc1 = __builtin_amdgcn_mfma_f32_16x16x32_bf16(a, Bk[1][kk], acc1, 0, 0, 0);
        }
        // z += h @ Wrk
#pragma unroll
        for (int kk = 0; kk < 8; ++kk) {
            union { unsigned long long uu[2]; short8 v; } ax;
            ax.uu[0] = ha[kk]; ax.uu[1] = hb2[kk];
            acc0 = __builtin_amdgcn_mfma_f32_16x16x32_bf16(ax.v, Bk[0][8 + kk], acc0, 0, 0, 0);
            acc1 = __builtin_amdgcn_mfma_f32_16x16x32_bf16(ax.v, Bk[1][8 + kk], acc1, 0, 0, 0);
        }

        // gates: acc0 = {i|f}, acc1 = {g|o}; pair (cid, cid^8) exchanges
        const bool lo = (cid < 8);
#pragma unroll
        for (int r = 0; r < 4; ++r) {
            const float x0 = __shfl_xor(acc0[r], 8, 64);
            const float x1 = __shfl_xor(acc1[r], 8, 64);
            const float zi = (lo ? acc0[r] : x0) + bi;
            const float zf = (lo ? x0 : acc0[r]) + bff;
            const float zg = (lo ? acc1[r] : x1) + bg;
            const float zo = (lo ? x1 : acc1[r]) + bo2;
            const float si = sigm(zi), sf = sigm(zf), so = sigm(zo), tg = tanh_(zg);
            cc[r] = sf * cc[r] + si * tg;
            h[r]  = so * tanh_(cc[r]);
        }

        // wave-local transpose: [r][unit] packing for 8-byte publish
        if (cid < 8) {
#pragma unroll
            for (int r = 0; r < 4; ++r)
                hx[w][(q * 4 + r) * 8 + cid] = f2bf(h[r]);
        }
        __builtin_amdgcn_wave_barrier();   // same-wave DS ops are in-order

        // publish h^{s+1} to slot (s+1)&1 + release flag
        if (lane < 32) {
            const int r = lane >> 1, half = lane & 1;
            const int u0 = g * 32 + w * 8 + half * 4;
            const unsigned long long pk = *(const unsigned long long*)&hx[w][r * 8 + half * 4];
            __hip_atomic_store((unsigned long long*)hbuf
                                   + ((size_t)(((s + 1) & 1) * 32 + m) * 16 + r) * 64 + (u0 >> 2),
                               pk, __ATOMIC_RELAXED, __HIP_MEMORY_SCOPE_AGENT);
        }
        if (s == NSTEP - 1 && cid < 8) {
            // fp32 final h for the head
#pragma unroll
            for (int r = 0; r < 4; ++r)
                __hip_atomic_store(&hfin[((size_t)m * 16 + q * 4 + r) * 256 + u], h[r],
                                   __ATOMIC_RELAXED, __HIP_MEMORY_SCOPE_AGENT);
        }
        if (lane == 32)
            __hip_atomic_store(&flags[(m * 32 + g * 4 + w) * 16], (unsigned)(s + 2),
                               __ATOMIC_RELEASE, __HIP_MEMORY_SCOPE_AGENT);

        // store x^{s+1} to the other LDS buffer
        if (s < NSTEP - 1) {
            const int row = tid >> 4, c16 = tid & 15;
#pragma unroll
            for (int jj = 0; jj < 4; ++jj) {
                const int col = jj * 64 + c16 * 4;
                unsigned long long pk = (unsigned long long)f2bf(xp[jj].x)
                    | ((unsigned long long)f2bf(xp[jj].y) << 16)
                    | ((unsigned long long)f2bf(xp[jj].z) << 32)
                    | ((unsigned long long)f2bf(xp[jj].w) << 48);
                *(unsigned long long*)&xb[(s + 1) & 1][row * 264 + col] = pk;
            }
        }
        __syncthreads();
    }

    // ---- head: g==0 blocks compute out = relu(h255 . Wo + bo) ----
    if (g == 0) {
        const unsigned target = (unsigned)(NSTEP + 1);
        for (;;) {
            unsigned v = 0xFFFFFFFFu;
            if (lane < 32)
                v = __hip_atomic_load(&flags[(m * 32 + lane) * 16],
                                      __ATOMIC_ACQUIRE, __HIP_MEMORY_SCOPE_AGENT);
            if (!__any((int)(v < target))) break;
            __builtin_amdgcn_s_sleep(1);
        }
        const int r = w * 4 + q;          // row within tile
        float part = 0.0f;
#pragma unroll
        for (int jj = 0; jj < 4; ++jj) {
            const int u0 = cid * 16 + jj * 4;
            const float4 wv = *(const float4*)(Wo + u0);
            float hv0 = __hip_atomic_load(&hfin[((size_t)m * 16 + r) * 256 + u0 + 0], __ATOMIC_RELAXED, __HIP_MEMORY_SCOPE_AGENT);
            float hv1 = __hip_atomic_load(&hfin[((size_t)m * 16 + r) * 256 + u0 + 1], __ATOMIC_RELAXED, __HIP_MEMORY_SCOPE_AGENT);
            float hv2 = __hip_atomic_load(&hfin[((size_t)m * 16 + r) * 256 + u0 + 2], __ATOMIC_RELAXED, __HIP_MEMORY_SCOPE_AGENT);
            float hv3 = __hip_atomic_load(&hfin[((size_t)m * 16 + r) * 256 + u0 + 3], __ATOMIC_RELAXED, __HIP_MEMORY_SCOPE_AGENT);
            part += hv0 * wv.x + hv1 * wv.y + hv2 * wv.z + hv3 * wv.w;
        }
#pragma unroll
        for (int msk = 8; msk > 0; msk >>= 1) part += __shfl_xor(part, msk, 16);
        if (cid == 0) out[m0 + r] = fmaxf(part + bo_p[0], 0.0f);
    }
}

// ---------------------------------------------------------------------------
extern "C" void kernel_launch(void* const* d_in, const int* in_sizes, int n_in,
                              void* d_out, int out_size, void* d_ws, size_t ws_size,
                              hipStream_t stream)
{
    const float* motion = (const float*)d_in[0];
    const float* robot  = (const float*)d_in[1];
    const float* osr    = (const float*)d_in[2];
    const float* osi    = (const float*)d_in[3];
    const float* hist   = (const float*)d_in[4];
    const float* act    = (const float*)d_in[5];
    const float* ore    = (const float*)d_in[6];
    const float* oie    = (const float*)d_in[7];
    const float* Wm  = (const float*)d_in[8];  const float* bm  = (const float*)d_in[9];
    const float* Wr  = (const float*)d_in[10]; const float* br  = (const float*)d_in[11];
    const float* Wre = (const float*)d_in[12]; const float* bre = (const float*)d_in[13];
    const float* Wim = (const float*)d_in[14]; const float* bim = (const float*)d_in[15];
    const float* Wc  = (const float*)d_in[16]; const float* bc  = (const float*)d_in[17];
    const float* Wk  = (const float*)d_in[18];
    const float* Wrk = (const float*)d_in[19];
    const float* bl  = (const float*)d_in[20];
    const float* Wo  = (const float*)d_in[21]; const float* bo  = (const float*)d_in[22];

    char* ws = (char*)d_ws;
    float*          state = (float*)(ws + 0);                  // 524288
    unsigned short* W2    = (unsigned short*)(ws + 524288);    // 1048576
    unsigned short* hbuf  = (unsigned short*)(ws + 1572864);   // 524288 (2 slots)
    unsigned int*   flags = (unsigned int*)(ws + 2097152);     // 65536
    float*          hfin  = (float*)(ws + 2162688);            // 524288
    float*          out   = (float*)d_out;                     // total ws: 2686976 B

    encoder_kernel<<<dim3(32), dim3(256), 0, stream>>>(
        motion, robot, osr, osi, ore, oie,
        Wm, bm, Wr, br, Wre, bre, Wim, bim, Wc, bc, state);
    prep_kernel<<<dim3(1024), dim3(256), 0, stream>>>(Wk, Wrk, W2, flags);
    lstm_kernel<<<dim3(256), dim3(256), 0, stream>>>(
        hist, act, state, W2, bl, Wo, bo, hbuf, flags, hfin, out);
}

// Round 3
// 2331.598 us; speedup vs baseline: 2.8242x; 2.8242x over previous
//
#include <hip/hip_runtime.h>
#include <stdint.h>

// ---------------------------------------------------------------------------
// Critic: encoder -> 255-step LSTM (U=256, D_in=256) -> 1-unit relu head. B=512
//
// Round-3 design (fix: round 2's agent-atomic exchange storm):
//  - x@Wk hoisted out of the recurrence: 224 producer blocks compute
//    z_pre[s] = x_s@Wk + bl into a ring buffer (window-granular handoff,
//    one agent release/acquire per 8 steps — cheap and XCD-correct).
//  - 32 consumer blocks (1 batch-tile of 16 rows each) run the recurrence
//    with Wrk register-resident (12/16 tiles per wave, 384 VGPR/lane) +
//    LDS-resident (4/16 tiles, 128 KB). h in block-local LDS (double
//    buffered), c in registers. Zero cross-block traffic per step.
//  - Gate layout: tile quads {i,f,g,o} over the same 16 units -> gate math
//    fully lane-local, no shuffles.
// ---------------------------------------------------------------------------

#define NSTEP 255

typedef __attribute__((ext_vector_type(8))) short short8;   // 8 x bf16
typedef __attribute__((ext_vector_type(4))) float f32x4;

__device__ __forceinline__ unsigned short f2bf(float f) {
    union { float f; unsigned int u; } v; v.f = f;
    unsigned int r = v.u + 0x7FFFu + ((v.u >> 16) & 1u);   // RNE
    return (unsigned short)(r >> 16);
}
__device__ __forceinline__ float bf2f(unsigned short u) {
    union { float f; unsigned int v; } x; x.v = ((unsigned int)u) << 16; return x.f;
}
__device__ __forceinline__ float fexp2(float x) { return __builtin_amdgcn_exp2f(x); }
__device__ __forceinline__ float frcp(float x)  { return __builtin_amdgcn_rcpf(x); }
__device__ __forceinline__ float sigm(float x)  { return frcp(1.0f + fexp2(-1.44269504f * x)); }
__device__ __forceinline__ float tanh_(float x) { return 1.0f - 2.0f * frcp(1.0f + fexp2(2.88539008f * x)); }

// ---------------------------------------------------------------------------
// Encoder: state = relu(concat(ms,rs,re,im) @ Wc + bc)   [512,256] fp32
// ---------------------------------------------------------------------------
__global__ __launch_bounds__(256)
void encoder_kernel(const float* __restrict__ motion, const float* __restrict__ robot,
                    const float* __restrict__ osr, const float* __restrict__ osi,
                    const float* __restrict__ ore, const float* __restrict__ oie,
                    const float* __restrict__ Wm, const float* __restrict__ bm,
                    const float* __restrict__ Wr, const float* __restrict__ br,
                    const float* __restrict__ Wre, const float* __restrict__ bre,
                    const float* __restrict__ Wim, const float* __restrict__ bim,
                    const float* __restrict__ Wc, const float* __restrict__ bc,
                    float* __restrict__ state)
{
    __shared__ float in_m[16][64];
    __shared__ float in_r[16][128];
    __shared__ float in_re[16][128];
    __shared__ float in_im[16][128];
    __shared__ float catb[16 * 768];
    const int t = threadIdx.x;
    const int m0 = blockIdx.x * 16;

    {
        int idx = t * 4; int row = idx >> 6, col = idx & 63;
        *(float4*)&in_m[row][col]       = *(const float4*)(motion + (m0 + row) * 64 + col);
        *(float4*)&in_re[row][col]      = *(const float4*)(osr + (m0 + row) * 64 + col);
        *(float4*)&in_re[row][64 + col] = *(const float4*)(ore + (m0 + row) * 64 + col);
        *(float4*)&in_im[row][col]      = *(const float4*)(osi + (m0 + row) * 64 + col);
        *(float4*)&in_im[row][64 + col] = *(const float4*)(oie + (m0 + row) * 64 + col);
    }
    for (int p = 0; p < 2; ++p) {
        int idx = (t + p * 256) * 4; int row = idx >> 7, col = idx & 127;
        *(float4*)&in_r[row][col] = *(const float4*)(robot + (m0 + row) * 128 + col);
    }
    __syncthreads();

    for (int row = 0; row < 16; ++row) {
        {
            float s = bm[t];
            for (int k = 0; k < 64; ++k) s += in_m[row][k] * Wm[k * 256 + t];
            catb[row * 768 + t] = fmaxf(s, 0.0f);
        }
        {
            float s = br[t];
            for (int k = 0; k < 128; ++k) s += in_r[row][k] * Wr[k * 256 + t];
            catb[row * 768 + 256 + t] = fmaxf(s, 0.0f);
        }
        if (t < 128) {
            float s = bre[t];
            for (int k = 0; k < 128; ++k) s += in_re[row][k] * Wre[k * 128 + t];
            catb[row * 768 + 512 + t] = fmaxf(s, 0.0f);
        } else {
            const int u = t - 128;
            float s = bim[u];
            for (int k = 0; k < 128; ++k) s += in_im[row][k] * Wim[k * 128 + u];
            catb[row * 768 + 640 + u] = fmaxf(s, 0.0f);
        }
    }
    __syncthreads();

    for (int r0 = 0; r0 < 16; r0 += 4) {
        float a0 = bc[t], a1 = bc[t], a2 = bc[t], a3 = bc[t];
        for (int j = 0; j < 768; ++j) {
            const float wv = Wc[j * 256 + t];
            a0 += catb[(r0 + 0) * 768 + j] * wv;
            a1 += catb[(r0 + 1) * 768 + j] * wv;
            a2 += catb[(r0 + 2) * 768 + j] * wv;
            a3 += catb[(r0 + 3) * 768 + j] * wv;
        }
        state[(m0 + r0 + 0) * 256 + t] = fmaxf(a0, 0.0f);
        state[(m0 + r0 + 1) * 256 + t] = fmaxf(a1, 0.0f);
        state[(m0 + r0 + 2) * 256 + t] = fmaxf(a2, 0.0f);
        state[(m0 + r0 + 3) * 256 + t] = fmaxf(a3, 0.0f);
    }
}

// ---------------------------------------------------------------------------
// Prep: W2k/W2r in frag-linear layout [(T*8+kk)*64+lane][8], bf16.
//   Tile T = wv*16 + gam*4 + g  -> orig col = g*256 + wv*64 + gam*16 + cid
//   frag element j: k = kk*32 + (lane>>4)*8 + j  (B layout: n=lane&15).
// blr2[T*64+lane] = bl[orig col].  Also zero flags.
// ---------------------------------------------------------------------------
__global__ __launch_bounds__(256)
void prep_kernel(const float* __restrict__ Wk, const float* __restrict__ Wrk,
                 const float* __restrict__ bl,
                 unsigned short* __restrict__ W2k, unsigned short* __restrict__ W2r,
                 float* __restrict__ blr2,
                 unsigned int* __restrict__ prod_flag, unsigned int* __restrict__ cons_prog)
{
    const int blk = blockIdx.x, t = threadIdx.x;
    if (blk < 256) {
        const int mat = blk >> 7;
        const int idx = (blk & 127) * 256 + t;      // (T*8+kk)*64+lane
        const int T = idx >> 9, kk = (idx >> 6) & 7, lane = idx & 63;
        const int q = lane >> 4, cid = lane & 15;
        const int wv = T >> 4, gam = (T >> 2) & 3, g = T & 3;
        const int col = g * 256 + wv * 64 + gam * 16 + cid;
        const float* W = mat ? Wrk : Wk;
        unsigned short* O = mat ? W2r : W2k;
#pragma unroll
        for (int j = 0; j < 8; ++j) {
            const int k = kk * 32 + q * 8 + j;
            O[(size_t)idx * 8 + j] = f2bf(W[(size_t)k * 1024 + col]);
        }
    } else {
        for (int e = t; e < 4096; e += 256) {
            const int T = e >> 6, lane = e & 63, cid = lane & 15;
            const int wv = T >> 4, gam = (T >> 2) & 3, g = T & 3;
            blr2[e] = bl[g * 256 + wv * 64 + gam * 16 + cid];
        }
        for (int i = t; i < 40960; i += 256) prod_flag[i] = 0u;
        for (int i = t; i < 512; i += 256) cons_prog[i] = 0u;
    }
}

// ---------------------------------------------------------------------------
// Fused: blocks 0..31 = consumers (recurrence), 32..255 = producers (z_pre).
// ---------------------------------------------------------------------------
__global__ __launch_bounds__(256, 1)
void fused_kernel(const float* __restrict__ hist, const float* __restrict__ act,
                  const float* __restrict__ state,
                  const unsigned short* __restrict__ W2k, const unsigned short* __restrict__ W2r,
                  const float* __restrict__ blr2,
                  const float* __restrict__ Wo, const float* __restrict__ bo_p,
                  unsigned short* __restrict__ zring,
                  unsigned int* __restrict__ prod_flag, unsigned int* __restrict__ cons_prog,
                  float* __restrict__ out,
                  int WSH, int NW, int RS, int ring_steps)
{
    __shared__ __align__(16) unsigned char smem[147968];
    unsigned short* ldsW = (unsigned short*)smem;                 // 131072 B (W tiles 12..15)
    unsigned short* hbuf0 = (unsigned short*)(smem + 131072);     // 8448 B
    unsigned short* hbuf1 = (unsigned short*)(smem + 139520);     // 8448 B

    const int tid = threadIdx.x;
    const int wv = tid >> 6, lane = tid & 63, q = lane >> 4, cid = lane & 15;
    const int bx = blockIdx.x;
    const int WIN = 1 << WSH, WMASK = WIN - 1;
    unsigned long long* zr64 = (unsigned long long*)zring;

    if (bx < 32) {
        // ======================= CONSUMER =======================
        const int m = bx, m0 = m * 16;

        // resident Wrk: tiles 0..11 of this wave
        short8 Wres[12][8];
#pragma unroll
        for (int t = 0; t < 12; ++t) {
#pragma unroll
            for (int kk = 0; kk < 8; ++kk)
                Wres[t][kk] = *(const short8*)(W2r + ((size_t)((wv * 16 + t) * 8 + kk) * 64 + lane) * 8);
        }
        // LDS-resident Wrk: tiles 12..15
#pragma unroll
        for (int t = 0; t < 4; ++t) {
#pragma unroll
            for (int kk = 0; kk < 8; ++kk) {
                short8 f = *(const short8*)(W2r + ((size_t)((wv * 16 + 12 + t) * 8 + kk) * 64 + lane) * 8);
                *(short8*)(ldsW + (((wv * 4 + t) * 8 + kk) * 64 + lane) * 8) = f;
            }
        }
        // h^0 = bf16(state tile)
        {
            const int row = tid >> 4, c0 = (tid & 15) * 16;
#pragma unroll
            for (int i = 0; i < 4; ++i) {
                const float4 v = *(const float4*)(state + (size_t)(m0 + row) * 256 + c0 + i * 4);
                unsigned long long pk = (unsigned long long)f2bf(v.x)
                    | ((unsigned long long)f2bf(v.y) << 16)
                    | ((unsigned long long)f2bf(v.z) << 32)
                    | ((unsigned long long)f2bf(v.w) << 48);
                *(unsigned long long*)&hbuf0[row * 264 + c0 + i * 4] = pk;
            }
        }
        // c^0
        float cc[16];
#pragma unroll
        for (int g4 = 0; g4 < 4; ++g4)
#pragma unroll
            for (int r = 0; r < 4; ++r)
                cc[g4 * 4 + r] = state[(size_t)(m0 + q * 4 + r) * 256 + wv * 64 + g4 * 16 + cid];

        __syncthreads();

        unsigned short* hcur = hbuf0;
        unsigned short* hnxt = hbuf1;
        float hlast[16];
        int zslot = 0;

        for (int s = 0; s < NSTEP; ++s) {
            if ((s & WMASK) == 0) {
                const int f = s >> WSH;
                while (__hip_atomic_load(&prod_flag[(f * 32 + m) * 4],
                                         __ATOMIC_ACQUIRE, __HIP_MEMORY_SCOPE_AGENT) == 0)
                    __builtin_amdgcn_s_sleep(1);
            }
            const unsigned long long* zb = zr64 + ((size_t)zslot * 32 + m) * 4096 + lane;

            unsigned long long z1[8];
#pragma unroll
            for (int t = 0; t < 8; ++t) z1[t] = zb[(wv * 16 + t) * 64];

            // pass 1: tiles 0..7 (gamma 0,1), all resident
            f32x4 acc[8];
#pragma unroll
            for (int t = 0; t < 8; ++t) acc[t] = (f32x4){0.f, 0.f, 0.f, 0.f};
            const unsigned short* hrow = hcur + cid * 264 + q * 8;
#pragma unroll
            for (int kk = 0; kk < 8; ++kk) {
                const short8 a = *(const short8*)(hrow + kk * 32);
#pragma unroll
                for (int t = 0; t < 8; ++t)
                    acc[t] = __builtin_amdgcn_mfma_f32_16x16x32_bf16(a, Wres[t][kk], acc[t], 0, 0, 0);
            }

            unsigned long long z2[8];
#pragma unroll
            for (int t = 0; t < 8; ++t) z2[t] = zb[(wv * 16 + 8 + t) * 64];

            const bool last = (s == NSTEP - 1);
#pragma unroll
            for (int g4 = 0; g4 < 2; ++g4) {
#pragma unroll
                for (int r = 0; r < 4; ++r) {
                    const float zi = acc[g4 * 4 + 0][r] + bf2f((unsigned short)(z1[g4 * 4 + 0] >> (16 * r)));
                    const float zf = acc[g4 * 4 + 1][r] + bf2f((unsigned short)(z1[g4 * 4 + 1] >> (16 * r)));
                    const float zg = acc[g4 * 4 + 2][r] + bf2f((unsigned short)(z1[g4 * 4 + 2] >> (16 * r)));
                    const float zo = acc[g4 * 4 + 3][r] + bf2f((unsigned short)(z1[g4 * 4 + 3] >> (16 * r)));
                    const float c = sigm(zf) * cc[g4 * 4 + r] + sigm(zi) * tanh_(zg);
                    cc[g4 * 4 + r] = c;
                    const float h = sigm(zo) * tanh_(c);
                    hnxt[(q * 4 + r) * 264 + wv * 64 + g4 * 16 + cid] = f2bf(h);
                    if (last) hlast[g4 * 4 + r] = h;
                }
            }

            // pass 2: tiles 8..15 (gamma 2,3), 8..11 resident + 12..15 LDS
#pragma unroll
            for (int t = 0; t < 8; ++t) acc[t] = (f32x4){0.f, 0.f, 0.f, 0.f};
#pragma unroll
            for (int kk = 0; kk < 8; ++kk) {
                const short8 a = *(const short8*)(hrow + kk * 32);
#pragma unroll
                for (int t = 0; t < 4; ++t)
                    acc[t] = __builtin_amdgcn_mfma_f32_16x16x32_bf16(a, Wres[8 + t][kk], acc[t], 0, 0, 0);
#pragma unroll
                for (int t = 0; t < 4; ++t) {
                    const short8 b = *(const short8*)(ldsW + (((wv * 4 + t) * 8 + kk) * 64 + lane) * 8);
                    acc[4 + t] = __builtin_amdgcn_mfma_f32_16x16x32_bf16(a, b, acc[4 + t], 0, 0, 0);
                }
            }
#pragma unroll
            for (int g4 = 0; g4 < 2; ++g4) {
#pragma unroll
                for (int r = 0; r < 4; ++r) {
                    const float zi = acc[g4 * 4 + 0][r] + bf2f((unsigned short)(z2[g4 * 4 + 0] >> (16 * r)));
                    const float zf = acc[g4 * 4 + 1][r] + bf2f((unsigned short)(z2[g4 * 4 + 1] >> (16 * r)));
                    const float zg = acc[g4 * 4 + 2][r] + bf2f((unsigned short)(z2[g4 * 4 + 2] >> (16 * r)));
                    const float zo = acc[g4 * 4 + 3][r] + bf2f((unsigned short)(z2[g4 * 4 + 3] >> (16 * r)));
                    const float c = sigm(zf) * cc[(g4 + 2) * 4 + r] + sigm(zi) * tanh_(zg);
                    cc[(g4 + 2) * 4 + r] = c;
                    const float h = sigm(zo) * tanh_(c);
                    hnxt[(q * 4 + r) * 264 + wv * 64 + (g4 + 2) * 16 + cid] = f2bf(h);
                    if (last) hlast[(g4 + 2) * 4 + r] = h;
                }
            }

            __syncthreads();
            { unsigned short* tmp = hcur; hcur = hnxt; hnxt = tmp; }
            if (((s + 1) & WMASK) == 0 && tid == 0)
                __hip_atomic_store(&cons_prog[m * 16], (unsigned)((s + 1) >> WSH),
                                   __ATOMIC_RELEASE, __HIP_MEMORY_SCOPE_AGENT);
            zslot = (zslot + 1 == ring_steps) ? 0 : zslot + 1;
        }

        // head: reuse ldsW region for fp32 final h
        float* hfin = (float*)smem;               // 16 x 256 f32 = 16384 B
        float* red  = (float*)(smem + 16384);     // 16 x 16 f32
#pragma unroll
        for (int g4 = 0; g4 < 4; ++g4)
#pragma unroll
            for (int r = 0; r < 4; ++r)
                hfin[(q * 4 + r) * 256 + wv * 64 + g4 * 16 + cid] = hlast[g4 * 4 + r];
        __syncthreads();
        {
            const int row = tid >> 4, c16 = tid & 15;
            float part = 0.0f;
#pragma unroll
            for (int j = 0; j < 16; ++j) {
                const int u = c16 + j * 16;
                part += hfin[row * 256 + u] * Wo[u];
            }
            red[row * 16 + c16] = part;
        }
        __syncthreads();
        if (tid < 16) {
            float sum = 0.0f;
#pragma unroll
            for (int j = 0; j < 16; ++j) sum += red[tid * 16 + j];
            out[m0 + tid] = fmaxf(sum + bo_p[0], 0.0f);
        }
    } else {
        // ======================= PRODUCER =======================
        const int p = bx - 32;
        const int total = NW * 32;
        for (int tau = p; tau < total; tau += 224) {
            const int w_ = tau >> 5, m = tau & 31, m0 = m * 16;
            const int nst = min(WIN, NSTEP - w_ * WIN);
            if (w_ >= RS) {
                const unsigned need = (unsigned)(w_ - RS + 1);
                while (__hip_atomic_load(&cons_prog[m * 16],
                                         __ATOMIC_ACQUIRE, __HIP_MEMORY_SCOPE_AGENT) < need)
                    __builtin_amdgcn_s_sleep(4);
            }
            // this wave's steps (stride 4 over the window)
            int ns_my = 0; int sabs[2] = {0, 0};
            for (int sl = wv; sl < nst; sl += 4) { if (ns_my < 2) sabs[ns_my++] = w_ * WIN + sl; }

            short8 A2[2][8];
#pragma unroll
            for (int si = 0; si < 2; ++si) {
                if (si < ns_my) {
                    const int s = sabs[si];
                    const float* xs = (s < 127)
                        ? hist + ((size_t)(m0 + cid) * 128 + s) * 256
                        : act + ((size_t)(m0 + cid) * 128 + (s - 127)) * 256;
#pragma unroll
                    for (int kk = 0; kk < 8; ++kk) {
                        const float4 a = *(const float4*)(xs + kk * 32 + q * 8);
                        const float4 b = *(const float4*)(xs + kk * 32 + q * 8 + 4);
                        union { unsigned short us[8]; short8 v; } pk;
                        pk.us[0] = f2bf(a.x); pk.us[1] = f2bf(a.y);
                        pk.us[2] = f2bf(a.z); pk.us[3] = f2bf(a.w);
                        pk.us[4] = f2bf(b.x); pk.us[5] = f2bf(b.y);
                        pk.us[6] = f2bf(b.z); pk.us[7] = f2bf(b.w);
                        A2[si][kk] = pk.v;
                    }
                }
            }
            if (ns_my > 0) {
                for (int Tc = 0; Tc < 16; ++Tc) {
                    float bias[4];
#pragma unroll
                    for (int t = 0; t < 4; ++t) bias[t] = blr2[(Tc * 4 + t) * 64 + lane];
                    f32x4 acc[2][4];
#pragma unroll
                    for (int si = 0; si < 2; ++si)
#pragma unroll
                        for (int t = 0; t < 4; ++t)
                            acc[si][t] = (f32x4){bias[t], bias[t], bias[t], bias[t]};
#pragma unroll
                    for (int kk = 0; kk < 8; ++kk) {
                        short8 Wf[4];
#pragma unroll
                        for (int t = 0; t < 4; ++t)
                            Wf[t] = *(const short8*)(W2k + ((size_t)((Tc * 4 + t) * 8 + kk) * 64 + lane) * 8);
#pragma unroll
                        for (int t = 0; t < 4; ++t) {
                            acc[0][t] = __builtin_amdgcn_mfma_f32_16x16x32_bf16(A2[0][kk], Wf[t], acc[0][t], 0, 0, 0);
                            if (ns_my > 1)
                                acc[1][t] = __builtin_amdgcn_mfma_f32_16x16x32_bf16(A2[1][kk], Wf[t], acc[1][t], 0, 0, 0);
                        }
                    }
#pragma unroll
                    for (int si = 0; si < 2; ++si) {
                        if (si < ns_my) {
                            const int zsl = sabs[si] % ring_steps;
#pragma unroll
                            for (int t = 0; t < 4; ++t) {
                                unsigned long long pk = (unsigned long long)f2bf(acc[si][t][0])
                                    | ((unsigned long long)f2bf(acc[si][t][1]) << 16)
                                    | ((unsigned long long)f2bf(acc[si][t][2]) << 32)
                                    | ((unsigned long long)f2bf(acc[si][t][3]) << 48);
                                zr64[((size_t)zsl * 32 + m) * 4096 + (Tc * 4 + t) * 64 + lane] = pk;
                            }
                        }
                    }
                }
            }
            __syncthreads();
            if (tid == 0)
                __hip_atomic_store(&prod_flag[(w_ * 32 + m) * 4], 1u,
                                   __ATOMIC_RELEASE, __HIP_MEMORY_SCOPE_AGENT);
        }
    }
}

// ---------------------------------------------------------------------------
extern "C" void kernel_launch(void* const* d_in, const int* in_sizes, int n_in,
                              void* d_out, int out_size, void* d_ws, size_t ws_size,
                              hipStream_t stream)
{
    const float* motion = (const float*)d_in[0];
    const float* robot  = (const float*)d_in[1];
    const float* osr    = (const float*)d_in[2];
    const float* osi    = (const float*)d_in[3];
    const float* hist   = (const float*)d_in[4];
    const float* act    = (const float*)d_in[5];
    const float* ore    = (const float*)d_in[6];
    const float* oie    = (const float*)d_in[7];
    const float* Wm  = (const float*)d_in[8];  const float* bm  = (const float*)d_in[9];
    const float* Wr  = (const float*)d_in[10]; const float* br  = (const float*)d_in[11];
    const float* Wre = (const float*)d_in[12]; const float* bre = (const float*)d_in[13];
    const float* Wim = (const float*)d_in[14]; const float* bim = (const float*)d_in[15];
    const float* Wc  = (const float*)d_in[16]; const float* bc  = (const float*)d_in[17];
    const float* Wk  = (const float*)d_in[18];
    const float* Wrk = (const float*)d_in[19];
    const float* bl  = (const float*)d_in[20];
    const float* Wo  = (const float*)d_in[21]; const float* bo  = (const float*)d_in[22];

    char* ws = (char*)d_ws;
    float*          state     = (float*)(ws + 0);                  // 524288
    unsigned short* W2k       = (unsigned short*)(ws + 524288);    // 524288
    unsigned short* W2r       = (unsigned short*)(ws + 1048576);   // 524288
    float*          blr2      = (float*)(ws + 1572864);            // 16384
    unsigned int*   prod_flag = (unsigned int*)(ws + 1589248);     // 163840
    unsigned int*   cons_prog = (unsigned int*)(ws + 1753088);     // 2048
    unsigned short* zring     = (unsigned short*)(ws + 1757184);   // ring
    float*          out       = (float*)d_out;

    // adaptive ring: per-step z is 1 MB (32 tiles x 32 KB)
    size_t avail = (ws_size > 1757184) ? ws_size - 1757184 : 0;
    long rs_max = (long)(avail / 1048576);
    int WIN = 1, NW = 255, RS = 1;
    const int wins[4] = {8, 4, 2, 1};
    for (int i = 0; i < 4; ++i) {
        const int Wn = wins[i];
        const int nw = (NSTEP + Wn - 1) / Wn;
        long rs = rs_max / Wn; if (rs > nw) rs = nw;
        if (rs >= 2) { WIN = Wn; NW = nw; RS = (int)rs; break; }
        if (Wn == 1) { WIN = 1; NW = nw; RS = (int)(rs >= 1 ? rs : 1); }
    }
    int ring_steps = RS * WIN; if (ring_steps < 1) ring_steps = 1;
    const int WSH = (WIN == 8) ? 3 : (WIN == 4) ? 2 : (WIN == 2) ? 1 : 0;

    encoder_kernel<<<dim3(32), dim3(256), 0, stream>>>(
        motion, robot, osr, osi, ore, oie,
        Wm, bm, Wr, br, Wre, bre, Wim, bim, Wc, bc, state);
    prep_kernel<<<dim3(257), dim3(256), 0, stream>>>(
        Wk, Wrk, bl, W2k, W2r, blr2, prod_flag, cons_prog);
    fused_kernel<<<dim3(256), dim3(256), 0, stream>>>(
        hist, act, state, W2k, W2r, blr2, Wo, bo,
        zring, prod_flag, cons_prog, out, WSH, NW, RS, ring_steps);
}